// Round 12
// baseline (302.557 us; speedup 1.0000x reference)
//
#include <hip/hip_runtime.h>
#include <hip/hip_bf16.h>

typedef __attribute__((ext_vector_type(8))) short short8;
typedef __attribute__((ext_vector_type(4))) float f32x4;

#define KK 4096
#define NELEM 2097152
#define TAU 2.5e-4f

__device__ __forceinline__ unsigned short f2bf(float f) {
    unsigned u = __float_as_uint(f);
    u = (u + 0x7FFFu + ((u >> 16) & 1u)) >> 16;
    return (unsigned short)u;
}
__device__ __forceinline__ float bf2f(unsigned short h) {
    return __uint_as_float(((unsigned)h) << 16);
}

// ---------------- codebook prep: norms + bf16 hi/lo split + ws zeroing ----------------
__global__ void k_prep(const float* __restrict__ cb, float* __restrict__ cn,
                       unsigned short* __restrict__ cbh, unsigned short* __restrict__ cbl,
                       int* __restrict__ wszero) {
    if (blockIdx.x == 0) {           // zero ssd/gsum/gsq control region
        for (int i = threadIdx.x; i < 256; i += 256) wszero[i] = 0;
    }
    int t = blockIdx.x * 256 + threadIdx.x;       // 16384 threads
    int row = t >> 2, part = t & 3;
    const float4* p = (const float4*)(cb + (size_t)row * 64 + part * 16);
    float s = 0.f;
    short8 hv[2], lv[2];
#pragma unroll
    for (int i = 0; i < 4; i++) {
        float4 v = p[i];
        float arr[4] = {v.x, v.y, v.z, v.w};
#pragma unroll
        for (int j = 0; j < 4; j++) {
            float f = arr[j];
            s += f * f;
            int e = i * 4 + j;
            unsigned short h = f2bf(f);
            hv[e >> 3][e & 7] = (short)h;
            lv[e >> 3][e & 7] = (short)f2bf(f - bf2f(h));
        }
    }
    short8* oh = (short8*)(cbh + (size_t)row * 64 + part * 16);
    short8* ol = (short8*)(cbl + (size_t)row * 64 + part * 16);
    oh[0] = hv[0]; oh[1] = hv[1];
    ol[0] = lv[0]; ol[1] = lv[1];
    s += __shfl_xor(s, 1, 64);
    s += __shfl_xor(s, 2, 64);
    if (part == 0) cn[row] = s;
}

#define MFMA __builtin_amdgcn_mfma_f32_16x16x32_bf16

// ---- M-split fused: conv_in + full-codebook MFMA argmin + inline exact rescue
//      + gather + ssd + gn-stats. 1024 blocks = (b,h,half); 32 queries/block.
// Wave wv scans codes [wv*1024, +1024), 2 m-tiles/wave. 4 blocks/CU co-resident.
__global__ __launch_bounds__(256, 2) void k_argmin(
    const float* __restrict__ x, const float* __restrict__ ciw, const float* __restrict__ cib,
    const unsigned short* __restrict__ cbh, const unsigned short* __restrict__ cbl,
    const float* __restrict__ cn, const float* __restrict__ cb,
    float* __restrict__ quant, float* __restrict__ ssd,
    float* __restrict__ gsum, float* __restrict__ gsq) {

    __shared__ float    slab[3][3][66];
    __shared__ unsigned qtile[32][65];
    __shared__ float    qf32[32][65];
    __shared__ float    mb1[4][32];
    __shared__ float    mb2[4][32];
    __shared__ int      mi1[4][32];
    __shared__ int      fi[32];
    __shared__ float    gred[4][16];
    __shared__ int      nflag;
    __shared__ int      flagged[32];
    __shared__ float    rb[4];
    __shared__ int      ri[4];

    const int tid  = threadIdx.x;
    const int L    = tid & 63;
    const int wv   = tid >> 6;            // 0..3
    const int blk  = blockIdx.x;
    const int grp  = blk >> 1, half = blk & 1;
    const int b    = grp >> 6, h = grp & 63;

    // ---- stage x slab (zero halo; full row, cheap) ----
    if (tid == 0) nflag = 0;
    for (int idx = tid; idx < 594; idx += 256) {
        int ci = idx / 198, rem = idx - ci * 198;
        int kh = rem / 66,  colp = rem - kh * 66;
        int hh = h + kh - 1, ww = colp - 1;
        float v = 0.f;
        if (hh >= 0 && hh < 64 && ww >= 0 && ww < 64)
            v = x[((b * 3 + ci) << 12) + (hh << 6) + ww];
        slab[ci][kh][colp] = v;
    }
    __syncthreads();

    // ---- conv_in: thread (w_= tid&31, cg = tid>>5) computes 8 output channels ----
    {
        const int w_  = tid & 31;
        const int cg  = tid >> 5;              // 0..7
        const int wgl = (half << 5) + w_;      // global w in row
        float xv[27];
#pragma unroll
        for (int ci = 0; ci < 3; ci++)
#pragma unroll
            for (int kh = 0; kh < 3; kh++)
#pragma unroll
                for (int kw = 0; kw < 3; kw++)
                    xv[ci * 9 + kh * 3 + kw] = slab[ci][kh][wgl + kw];
#pragma unroll
        for (int j = 0; j < 8; j++) {
            int co = cg * 8 + j;
            float acc = cib[co];
#pragma unroll
            for (int t2 = 0; t2 < 27; t2++)
                acc = fmaf(xv[t2], ciw[co * 27 + t2], acc);
            unsigned short hbits = f2bf(acc);
            unsigned short lbits = f2bf(acc - bf2f(hbits));
            qf32[w_][co]  = acc;
            qtile[w_][co] = (unsigned)hbits | ((unsigned)lbits << 16);
        }
    }
    __syncthreads();

    // ---- build A fragments (2 m-tiles x 2 k-halves, hi+lo) ----
    const int col = L & 15, g = L >> 4;
    short8 qh[2][2], ql[2][2];
#pragma unroll
    for (int mt = 0; mt < 2; mt++) {
        int qrow = mt * 16 + col;
#pragma unroll
        for (int kh = 0; kh < 2; kh++) {
            int d0 = (kh * 4 + g) * 8;
#pragma unroll
            for (int e = 0; e < 8; e++) {
                unsigned u = qtile[qrow][d0 + e];
                qh[mt][kh][e] = (short)(u & 0xFFFFu);
                ql[mt][kh][e] = (short)(u >> 16);
            }
        }
    }

    // ---- K loop: 64 groups of 16 codes, direct global B loads, no barriers ----
    float vb1[2][4], vb2[2][4];
    int   vi1[2][4];
#pragma unroll
    for (int mt = 0; mt < 2; mt++)
#pragma unroll
        for (int e = 0; e < 4; e++) { vb1[mt][e] = 3.4e38f; vb2[mt][e] = 3.4e38f; vi1[mt][e] = 0; }

    const int cbase0 = wv << 10;          // 1024 codes per wave
    const unsigned short* ph = cbh + (size_t)(cbase0 + col) * 64;
    const unsigned short* pl = cbl + (size_t)(cbase0 + col) * 64;
    const float* pcn = cn + cbase0 + col;

    short8 c0h0, c0h1, c0l0, c0l1, c1h0, c1h1, c1l0, c1l1;
    float  cn0, cn1;

    auto LD = [&](int gi, short8& h0, short8& h1, short8& l0, short8& l1, float& cnv) {
        const short8* p0 = (const short8*)(ph + ((size_t)gi << 10));
        const short8* p1 = (const short8*)(pl + ((size_t)gi << 10));
        h0 = p0[g]; h1 = p0[4 + g]; l0 = p1[g]; l1 = p1[4 + g];
        cnv = pcn[gi << 4];
    };
    auto PROC = [&](int gi, short8& h0, short8& h1, short8& l0, short8& l1, float cnv) {
        int kvb = cbase0 + gi * 16 + col;
#pragma unroll
        for (int mt = 0; mt < 2; mt++) {
            f32x4 acc = {0.f, 0.f, 0.f, 0.f};
            acc = MFMA(qh[mt][0], h0, acc, 0, 0, 0);
            acc = MFMA(qh[mt][1], h1, acc, 0, 0, 0);
            acc = MFMA(qh[mt][0], l0, acc, 0, 0, 0);
            acc = MFMA(qh[mt][1], l1, acc, 0, 0, 0);
            acc = MFMA(ql[mt][0], h0, acc, 0, 0, 0);
            acc = MFMA(ql[mt][1], h1, acc, 0, 0, 0);
#pragma unroll
            for (int e = 0; e < 4; e++) {
                float s = fmaf(acc[e], -2.f, cnv);
                vb2[mt][e] = __builtin_amdgcn_fmed3f(s, vb1[mt][e], vb2[mt][e]);
                bool take = s < vb1[mt][e];
                vi1[mt][e] = take ? kvb : vi1[mt][e];
                vb1[mt][e] = take ? s : vb1[mt][e];
            }
        }
    };

    LD(0, c0h0, c0h1, c0l0, c0l1, cn0);
#pragma unroll 1
    for (int gi = 0; gi < 64; gi += 2) {
        LD(gi + 1, c1h0, c1h1, c1l0, c1l1, cn1);
        PROC(gi, c0h0, c0h1, c0l0, c0l1, cn0);
        int gn = gi + 2 <= 63 ? gi + 2 : 63;
        LD(gn, c0h0, c0h1, c0l0, c0l1, cn0);
        PROC(gi + 1, c1h0, c1h1, c1l0, c1l1, cn1);
    }

    // ---- cross-lane (col) top-2 merge, then cross-wave via LDS ----
#pragma unroll
    for (int mt = 0; mt < 2; mt++)
#pragma unroll
    for (int e = 0; e < 4; e++) {
        float b1 = vb1[mt][e], b2 = vb2[mt][e];
        int i1 = vi1[mt][e];
#pragma unroll
        for (int m = 1; m < 16; m <<= 1) {
            float ob1 = __shfl_xor(b1, m, 64);
            float ob2 = __shfl_xor(b2, m, 64);
            int   oi1 = __shfl_xor(i1, m, 64);
            float hi = fmaxf(b1, ob1);
            b2 = fminf(fminf(b2, ob2), hi);
            bool take = (ob1 < b1) || ((ob1 == b1) && (oi1 < i1));
            if (take) { b1 = ob1; i1 = oi1; }
        }
        if (col == 0) {
            int qloc = mt * 16 + g * 4 + e;    // 0..31
            mb1[wv][qloc] = b1; mb2[wv][qloc] = b2; mi1[wv][qloc] = i1;
        }
    }
    __syncthreads();

    if (tid < 32) {
        float b1 = mb1[0][tid], b2 = mb2[0][tid];
        int i1 = mi1[0][tid];
#pragma unroll
        for (int w2 = 1; w2 < 4; w2++) {
            float ob1 = mb1[w2][tid], ob2 = mb2[w2][tid];
            int   oi1 = mi1[w2][tid];
            float hi = fmaxf(b1, ob1);
            b2 = fminf(fminf(b2, ob2), hi);
            bool take = (ob1 < b1) || ((ob1 == b1) && (oi1 < i1));
            if (take) { b1 = ob1; i1 = oi1; }
        }
        fi[tid] = i1;
        if (b2 - b1 < TAU) {
            int p = atomicAdd(&nflag, 1);
            flagged[p] = tid;
        }
    }
    __syncthreads();

    // ---- inline exact fp32 rescue (block-local; typically 0 iterations) ----
    int nf = nflag;
    for (int r = 0; r < nf; r++) {
        int qf = flagged[r];
        float best = 3.4e38f; int bi = 0;
        for (int kk = 0; kk < 16; kk++) {
            int k = kk * 256 + tid;
            const float4* cp = (const float4*)(cb + (size_t)k * 64);
            float d0 = 0.f, d1 = 0.f, d2 = 0.f, d3 = 0.f;
#pragma unroll
            for (int i = 0; i < 16; i += 4) {
                float4 c0 = cp[i], c1 = cp[i+1], c2 = cp[i+2], c3 = cp[i+3];
                d0 += qf32[qf][4*i+ 0]*c0.x + qf32[qf][4*i+ 1]*c0.y + qf32[qf][4*i+ 2]*c0.z + qf32[qf][4*i+ 3]*c0.w;
                d1 += qf32[qf][4*i+ 4]*c1.x + qf32[qf][4*i+ 5]*c1.y + qf32[qf][4*i+ 6]*c1.z + qf32[qf][4*i+ 7]*c1.w;
                d2 += qf32[qf][4*i+ 8]*c2.x + qf32[qf][4*i+ 9]*c2.y + qf32[qf][4*i+10]*c2.z + qf32[qf][4*i+11]*c2.w;
                d3 += qf32[qf][4*i+12]*c3.x + qf32[qf][4*i+13]*c3.y + qf32[qf][4*i+14]*c3.z + qf32[qf][4*i+15]*c3.w;
            }
            float s = cn[k] - 2.f * ((d0 + d1) + (d2 + d3));
            if (s < best) { best = s; bi = k; }   // per-thread k increasing: keeps lowest
        }
#pragma unroll
        for (int off = 32; off; off >>= 1) {
            float ob = __shfl_down(best, off, 64);
            int   oi = __shfl_down(bi, off, 64);
            if (ob < best || (ob == best && oi < bi)) { best = ob; bi = oi; }
        }
        if (L == 0) { rb[wv] = best; ri[wv] = bi; }
        __syncthreads();
        if (tid == 0) {
            float bb = rb[0]; int ii = ri[0];
#pragma unroll
            for (int w2 = 1; w2 < 4; w2++)
                if (rb[w2] < bb || (rb[w2] == bb && ri[w2] < ii)) { bb = rb[w2]; ii = ri[w2]; }
            fi[qf] = ii;
        }
        __syncthreads();
    }

    // ---- gather + quant write (NCHW) + ssd + GN partial stats ----
    {
        int qloc = tid >> 3, part = tid & 7;          // part == GN group
        int idx = fi[qloc];
        int hw = (h << 6) + (half << 5) + qloc;
        const float* crow = cb + (size_t)idx * 64 + part * 8;
        float* qout = quant + ((size_t)b << 18) + ((size_t)(part * 8) << 12) + hw;
        float ps = 0.f, sA = 0.f, sA2 = 0.f;
#pragma unroll
        for (int cc = 0; cc < 8; cc++) {
            float fv = qf32[qloc][part * 8 + cc];
            float cv = crow[cc];
            float d = cv - fv;
            ps += d * d;
            sA += cv; sA2 += cv * cv;
            qout[(size_t)cc << 12] = cv;
        }
#pragma unroll
        for (int off = 32; off; off >>= 1) ps += __shfl_down(ps, off, 64);
        if (L == 0) atomicAdd(ssd, ps);
#pragma unroll
        for (int m = 8; m <= 32; m <<= 1) {
            sA  += __shfl_xor(sA, m, 64);
            sA2 += __shfl_xor(sA2, m, 64);
        }
        if (L < 8) {
            gred[wv][L * 2 + 0] = sA;
            gred[wv][L * 2 + 1] = sA2;
        }
    }
    __syncthreads();
    if (tid < 16) {
        float v = gred[0][tid] + gred[1][tid] + gred[2][tid] + gred[3][tid];
        int part = tid >> 1, stat = tid & 1;
        int g2 = b * 8 + part;
        atomicAdd(stat ? &gsq[g2] : &gsum[g2], v);
    }
}

// ---------------- fused GN + SiLU + conv_out (+ loss scalars) ----------------
__global__ __launch_bounds__(256, 2) void k_out(
    const float* __restrict__ quant,
    const float* __restrict__ gsum, const float* __restrict__ gsq,
    const float* __restrict__ scale, const float* __restrict__ bias,
    const float* __restrict__ dw, const float* __restrict__ db,
    const float* __restrict__ ssd, float* __restrict__ losses,
    float* __restrict__ out) {

    __shared__ float nls[64 * 3 * 66];    // [ci][kh][w+1], cols 0 & 65 zero-pad
    __shared__ float sc_s[64], bi_s[64];

    const int tid = threadIdx.x;
    const int blk = blockIdx.x;
    const int b = blk >> 6, h = blk & 63;

    if (blk == 0 && tid == 0) {
        float mean = ssd[0] / 2097152.f;
        losses[0] = mean;
        losses[1] = 0.25f * mean;
    }

    if (tid < 64) {
        int grp = b * 8 + (tid >> 3);
        float m = gsum[grp] * (1.f / 32768.f);
        float var = gsq[grp] * (1.f / 32768.f) - m * m;
        float r = rsqrtf(var + 1e-5f);
        float sc = scale[tid] * r;
        sc_s[tid] = sc;
        bi_s[tid] = bias[tid] - m * sc;
    }
    for (int idx = tid; idx < 384; idx += 256) {
        int ci = idx / 6, r2 = idx % 6;
        int kh = r2 >> 1, side = r2 & 1;
        nls[ci * 198 + kh * 66 + (side ? 65 : 0)] = 0.f;
    }
    __syncthreads();

#pragma unroll
    for (int i = 0; i < 48; i++) {
        int idx = tid + i * 256;
        int w_ = idx & 63;
        int t2 = idx >> 6;                 // ci*3+kh
        int kh = t2 % 3, ci = t2 / 3;
        int hh = h + kh - 1;
        float v = 0.f;
        if (hh >= 0 && hh < 64) {
            float qv = quant[((size_t)(b * 64 + ci) << 12) + (hh << 6) + w_];
            float y = qv * sc_s[ci] + bi_s[ci];
            v = y / (1.f + expf(-y));
        }
        nls[ci * 198 + kh * 66 + w_ + 1] = v;
    }
    __syncthreads();

    const int co = tid >> 6;               // wave-uniform
    const int w_ = tid & 63;
    if (co < 3) {
        float acc = db[co];
#pragma unroll 4
        for (int ci = 0; ci < 64; ci++) {
            const float* wt = dw + (size_t)(co * 64 + ci) * 9;
#pragma unroll
            for (int kh = 0; kh < 3; kh++) {
                const float* base = nls + ci * 198 + kh * 66 + w_;
                acc = fmaf(base[0], wt[kh * 3 + 0], acc);
                acc = fmaf(base[1], wt[kh * 3 + 1], acc);
                acc = fmaf(base[2], wt[kh * 3 + 2], acc);
            }
        }
        out[((size_t)(b * 3 + co) << 12) + (h << 6) + w_] = acc;
    }
}

extern "C" void kernel_launch(void* const* d_in, const int* in_sizes, int n_in,
                              void* d_out, int out_size, void* d_ws, size_t ws_size,
                              hipStream_t stream) {
    const float* x   = (const float*)d_in[0];
    const float* ciw = (const float*)d_in[1];
    const float* cib = (const float*)d_in[2];
    const float* cb  = (const float*)d_in[3];
    const float* gsc = (const float*)d_in[4];
    const float* gbi = (const float*)d_in[5];
    const float* dw  = (const float*)d_in[6];
    const float* db  = (const float*)d_in[7];

    float* out = (float*)d_out;
    char* wsb  = (char*)d_ws;

    float*          ssd  = (float*)wsb;                       // 4B
    float*          gsum = (float*)(wsb + 64);                // 256B
    float*          gsq  = (float*)(wsb + 320);               // 256B
    float*          cn   = (float*)(wsb + 4096);              // 16KB
    unsigned short* cbh  = (unsigned short*)(wsb + 131072);   // 512KB
    unsigned short* cbl  = (unsigned short*)(wsb + 655360);   // 512KB

    float* recon  = out;                    // 98304
    float* quant  = out + 98304;            // 2097152
    float* losses = out + 98304 + NELEM;    // 2

    k_prep   <<<64,   256, 0, stream>>>(cb, cn, cbh, cbl, (int*)wsb);
    k_argmin <<<1024, 256, 0, stream>>>(x, ciw, cib, cbh, cbl, cn, cb,
                                        quant, ssd, gsum, gsq);
    k_out    <<<512,  256, 0, stream>>>(quant, gsum, gsq, gsc, gbi, dw, db,
                                        ssd, losses, recon);
}

// Round 13
// 261.997 us; speedup vs baseline: 1.1548x; 1.1548x over previous
//
#include <hip/hip_runtime.h>
#include <hip/hip_bf16.h>

typedef __attribute__((ext_vector_type(8))) short short8;
typedef __attribute__((ext_vector_type(4))) float f32x4;

#define KK 4096
#define NELEM 2097152
#define TAU 2.5e-4f

__device__ __forceinline__ unsigned short f2bf(float f) {
    unsigned u = __float_as_uint(f);
    u = (u + 0x7FFFu + ((u >> 16) & 1u)) >> 16;
    return (unsigned short)u;
}
__device__ __forceinline__ float bf2f(unsigned short h) {
    return __uint_as_float(((unsigned)h) << 16);
}

// ---------------- codebook prep: norms + bf16 hi/lo split + ws zeroing ----------------
__global__ void k_prep(const float* __restrict__ cb, float* __restrict__ cn,
                       unsigned short* __restrict__ cbh, unsigned short* __restrict__ cbl,
                       int* __restrict__ wszero) {
    if (blockIdx.x == 0) {           // zero ssd/gsum/gsq control region
        for (int i = threadIdx.x; i < 256; i += 256) wszero[i] = 0;
    }
    int t = blockIdx.x * 256 + threadIdx.x;       // 16384 threads
    int row = t >> 2, part = t & 3;
    const float4* p = (const float4*)(cb + (size_t)row * 64 + part * 16);
    float s = 0.f;
    short8 hv[2], lv[2];
#pragma unroll
    for (int i = 0; i < 4; i++) {
        float4 v = p[i];
        float arr[4] = {v.x, v.y, v.z, v.w};
#pragma unroll
        for (int j = 0; j < 4; j++) {
            float f = arr[j];
            s += f * f;
            int e = i * 4 + j;
            unsigned short h = f2bf(f);
            hv[e >> 3][e & 7] = (short)h;
            lv[e >> 3][e & 7] = (short)f2bf(f - bf2f(h));
        }
    }
    short8* oh = (short8*)(cbh + (size_t)row * 64 + part * 16);
    short8* ol = (short8*)(cbl + (size_t)row * 64 + part * 16);
    oh[0] = hv[0]; oh[1] = hv[1];
    ol[0] = lv[0]; ol[1] = lv[1];
    s += __shfl_xor(s, 1, 64);
    s += __shfl_xor(s, 2, 64);
    if (part == 0) cn[row] = s;
}

#define MFMA __builtin_amdgcn_mfma_f32_16x16x32_bf16

// ---- fused single-pass: conv_in + full-codebook MFMA argmin + inline exact rescue
//      + gather + ssd + gn-stats. 512 blocks = (b,h), 256 thr (4 waves).
// Wave wv scans codes [wv*1024, +1024), 4 m-tiles/wave. Grid-limited to
// 2 blocks/CU -> up to 256 VGPR free: DEPTH-4 named-buffer prefetch pipeline
// (3-PROC ~540cyc distance > L2 latency) substitutes ILP for occupancy.
__global__ __launch_bounds__(256, 2) void k_argmin(
    const float* __restrict__ x, const float* __restrict__ ciw, const float* __restrict__ cib,
    const unsigned short* __restrict__ cbh, const unsigned short* __restrict__ cbl,
    const float* __restrict__ cn, const float* __restrict__ cb,
    float* __restrict__ quant, float* __restrict__ ssd,
    float* __restrict__ gsum, float* __restrict__ gsq) {

    __shared__ float    slab[3][3][66];
    __shared__ unsigned qtile[64][65];
    __shared__ float    qf32[64][65];
    __shared__ float    mb1[4][64];
    __shared__ float    mb2[4][64];
    __shared__ int      mi1[4][64];
    __shared__ int      fi[64];
    __shared__ float    gred[4][16];
    __shared__ int      nflag;
    __shared__ int      flagged[64];
    __shared__ float    rb[4];
    __shared__ int      ri[4];

    const int tid = threadIdx.x;
    const int L   = tid & 63;
    const int wv  = tid >> 6;             // 0..3
    const int grp = blockIdx.x;
    const int b   = grp >> 6, h = grp & 63;

    // ---- stage x slab (zero halo) ----
    if (tid == 0) nflag = 0;
    for (int idx = tid; idx < 594; idx += 256) {
        int ci = idx / 198, rem = idx - ci * 198;
        int kh = rem / 66,  colp = rem - kh * 66;
        int hh = h + kh - 1, ww = colp - 1;
        float v = 0.f;
        if (hh >= 0 && hh < 64 && ww >= 0 && ww < 64)
            v = x[((b * 3 + ci) << 12) + (hh << 6) + ww];
        slab[ci][kh][colp] = v;
    }
    __syncthreads();

    // ---- conv_in: thread (w_=L, cg=wv) computes 16 output channels ----
    {
        const int w_  = L;
        const int cgs = __builtin_amdgcn_readfirstlane(wv);
        float xv[27];
#pragma unroll
        for (int ci = 0; ci < 3; ci++)
#pragma unroll
            for (int kh = 0; kh < 3; kh++)
#pragma unroll
                for (int kw = 0; kw < 3; kw++)
                    xv[ci * 9 + kh * 3 + kw] = slab[ci][kh][w_ + kw];
#pragma unroll
        for (int j = 0; j < 16; j++) {
            int co = cgs * 16 + j;
            float acc = cib[co];
#pragma unroll
            for (int t2 = 0; t2 < 27; t2++)
                acc = fmaf(xv[t2], ciw[co * 27 + t2], acc);
            unsigned short hbits = f2bf(acc);
            unsigned short lbits = f2bf(acc - bf2f(hbits));
            qf32[w_][co]  = acc;
            qtile[w_][co] = (unsigned)hbits | ((unsigned)lbits << 16);
        }
    }
    __syncthreads();

    // ---- build A fragments (4 m-tiles x 2 k-halves, hi+lo) ----
    const int col = L & 15, g = L >> 4;
    short8 qh[4][2], ql[4][2];
#pragma unroll
    for (int mt = 0; mt < 4; mt++) {
        int qrow = mt * 16 + col;
#pragma unroll
        for (int kh = 0; kh < 2; kh++) {
            int d0 = (kh * 4 + g) * 8;
#pragma unroll
            for (int e = 0; e < 8; e++) {
                unsigned u = qtile[qrow][d0 + e];
                qh[mt][kh][e] = (short)(u & 0xFFFFu);
                ql[mt][kh][e] = (short)(u >> 16);
            }
        }
    }

    // ---- K loop: 64 groups of 16 codes, depth-4 named-buffer pipeline ----
    float vb1[4][4], vb2[4][4];
    int   vi1[4][4];
#pragma unroll
    for (int mt = 0; mt < 4; mt++)
#pragma unroll
        for (int e = 0; e < 4; e++) { vb1[mt][e] = 3.4e38f; vb2[mt][e] = 3.4e38f; vi1[mt][e] = 0; }

    const int cbase0 = wv << 10;          // 1024 codes per wave
    const unsigned short* ph = cbh + (size_t)(cbase0 + col) * 64;
    const unsigned short* pl = cbl + (size_t)(cbase0 + col) * 64;
    const float* pcn = cn + cbase0 + col;

#define DECLBUF(n) short8 bh0_##n, bh1_##n, bl0_##n, bl1_##n; float bcn_##n;
    DECLBUF(0) DECLBUF(1) DECLBUF(2) DECLBUF(3)

#define LDB(n, gidx) { int _g = (gidx); _g = _g < 63 ? _g : 63;                  \
        const short8* _p0 = (const short8*)(ph + ((size_t)_g << 10));            \
        const short8* _p1 = (const short8*)(pl + ((size_t)_g << 10));            \
        bh0_##n = _p0[g]; bh1_##n = _p0[4 + g];                                  \
        bl0_##n = _p1[g]; bl1_##n = _p1[4 + g];                                  \
        bcn_##n = pcn[_g << 4]; }

#define PROCB(n, gidx) { int kvb = cbase0 + (gidx) * 16 + col;                   \
        _Pragma("unroll")                                                        \
        for (int mt = 0; mt < 4; mt++) {                                         \
            f32x4 acc = {0.f, 0.f, 0.f, 0.f};                                    \
            acc = MFMA(qh[mt][0], bh0_##n, acc, 0, 0, 0);                        \
            acc = MFMA(qh[mt][1], bh1_##n, acc, 0, 0, 0);                        \
            acc = MFMA(qh[mt][0], bl0_##n, acc, 0, 0, 0);                        \
            acc = MFMA(qh[mt][1], bl1_##n, acc, 0, 0, 0);                        \
            acc = MFMA(ql[mt][0], bh0_##n, acc, 0, 0, 0);                        \
            acc = MFMA(ql[mt][1], bh1_##n, acc, 0, 0, 0);                        \
            _Pragma("unroll")                                                    \
            for (int e = 0; e < 4; e++) {                                        \
                float s = fmaf(acc[e], -2.f, bcn_##n);                           \
                vb2[mt][e] = __builtin_amdgcn_fmed3f(s, vb1[mt][e], vb2[mt][e]); \
                bool take = s < vb1[mt][e];                                      \
                vi1[mt][e] = take ? kvb : vi1[mt][e];                            \
                vb1[mt][e] = take ? s : vb1[mt][e];                              \
            }                                                                    \
        } }

    LDB(0, 0) LDB(1, 1) LDB(2, 2)
#pragma unroll 1
    for (int gi = 0; gi < 64; gi += 4) {
        LDB(3, gi + 3) PROCB(0, gi)
        LDB(0, gi + 4) PROCB(1, gi + 1)
        LDB(1, gi + 5) PROCB(2, gi + 2)
        LDB(2, gi + 6) PROCB(3, gi + 3)
    }

    // ---- cross-lane (col) top-2 merge, then cross-wave via LDS ----
#pragma unroll
    for (int mt = 0; mt < 4; mt++)
#pragma unroll
    for (int e = 0; e < 4; e++) {
        float b1 = vb1[mt][e], b2 = vb2[mt][e];
        int i1 = vi1[mt][e];
#pragma unroll
        for (int m = 1; m < 16; m <<= 1) {
            float ob1 = __shfl_xor(b1, m, 64);
            float ob2 = __shfl_xor(b2, m, 64);
            int   oi1 = __shfl_xor(i1, m, 64);
            float hi = fmaxf(b1, ob1);
            b2 = fminf(fminf(b2, ob2), hi);
            bool take = (ob1 < b1) || ((ob1 == b1) && (oi1 < i1));
            if (take) { b1 = ob1; i1 = oi1; }
        }
        if (col == 0) {
            int qloc = mt * 16 + g * 4 + e;
            mb1[wv][qloc] = b1; mb2[wv][qloc] = b2; mi1[wv][qloc] = i1;
        }
    }
    __syncthreads();

    if (tid < 64) {
        float b1 = mb1[0][tid], b2 = mb2[0][tid];
        int i1 = mi1[0][tid];
#pragma unroll
        for (int w2 = 1; w2 < 4; w2++) {
            float ob1 = mb1[w2][tid], ob2 = mb2[w2][tid];
            int   oi1 = mi1[w2][tid];
            float hi = fmaxf(b1, ob1);
            b2 = fminf(fminf(b2, ob2), hi);
            bool take = (ob1 < b1) || ((ob1 == b1) && (oi1 < i1));
            if (take) { b1 = ob1; i1 = oi1; }
        }
        fi[tid] = i1;
        if (b2 - b1 < TAU) {
            int p = atomicAdd(&nflag, 1);
            flagged[p] = tid;
        }
    }
    __syncthreads();

    // ---- inline exact fp32 rescue (block-local; typically 0 iterations) ----
    int nf = nflag;
    for (int r = 0; r < nf; r++) {
        int qf = flagged[r];
        float best = 3.4e38f; int bi = 0;
        for (int kk = 0; kk < 16; kk++) {
            int k = kk * 256 + tid;
            const float4* cp = (const float4*)(cb + (size_t)k * 64);
            float d0 = 0.f, d1 = 0.f, d2 = 0.f, d3 = 0.f;
#pragma unroll
            for (int i = 0; i < 16; i += 4) {
                float4 c0 = cp[i], c1 = cp[i+1], c2 = cp[i+2], c3 = cp[i+3];
                d0 += qf32[qf][4*i+ 0]*c0.x + qf32[qf][4*i+ 1]*c0.y + qf32[qf][4*i+ 2]*c0.z + qf32[qf][4*i+ 3]*c0.w;
                d1 += qf32[qf][4*i+ 4]*c1.x + qf32[qf][4*i+ 5]*c1.y + qf32[qf][4*i+ 6]*c1.z + qf32[qf][4*i+ 7]*c1.w;
                d2 += qf32[qf][4*i+ 8]*c2.x + qf32[qf][4*i+ 9]*c2.y + qf32[qf][4*i+10]*c2.z + qf32[qf][4*i+11]*c2.w;
                d3 += qf32[qf][4*i+12]*c3.x + qf32[qf][4*i+13]*c3.y + qf32[qf][4*i+14]*c3.z + qf32[qf][4*i+15]*c3.w;
            }
            float s = cn[k] - 2.f * ((d0 + d1) + (d2 + d3));
            if (s < best) { best = s; bi = k; }   // per-thread k increasing: keeps lowest
        }
#pragma unroll
        for (int off = 32; off; off >>= 1) {
            float ob = __shfl_down(best, off, 64);
            int   oi = __shfl_down(bi, off, 64);
            if (ob < best || (ob == best && oi < bi)) { best = ob; bi = oi; }
        }
        if (L == 0) { rb[wv] = best; ri[wv] = bi; }
        __syncthreads();
        if (tid == 0) {
            float bb = rb[0]; int ii = ri[0];
#pragma unroll
            for (int w2 = 1; w2 < 4; w2++)
                if (rb[w2] < bb || (rb[w2] == bb && ri[w2] < ii)) { bb = rb[w2]; ii = ri[w2]; }
            fi[qf] = ii;
        }
        __syncthreads();
    }

    // ---- gather + quant write (NCHW) + ssd + GN partial stats ----
    {
        int qloc = tid >> 2, part = tid & 3;
        int idx = fi[qloc];
        int q = (grp << 6) + qloc;
        int hw = q & 4095;
        const float* crow = cb + (size_t)idx * 64 + part * 16;
        float* qout = quant + ((size_t)b << 18) + ((size_t)(part * 16) << 12) + hw;
        float ps = 0.f, sA = 0.f, sA2 = 0.f, sB = 0.f, sB2 = 0.f;
#pragma unroll
        for (int cc = 0; cc < 16; cc++) {
            float fv = qf32[qloc][part * 16 + cc];
            float cv = crow[cc];
            float d = cv - fv;
            ps += d * d;
            if (cc < 8) { sA += cv; sA2 += cv * cv; } else { sB += cv; sB2 += cv * cv; }
            qout[(size_t)cc << 12] = cv;
        }
#pragma unroll
        for (int off = 32; off; off >>= 1) ps += __shfl_down(ps, off, 64);
        if (L == 0) atomicAdd(ssd, ps);
#pragma unroll
        for (int m = 4; m <= 32; m <<= 1) {
            sA  += __shfl_xor(sA, m, 64);  sA2 += __shfl_xor(sA2, m, 64);
            sB  += __shfl_xor(sB, m, 64);  sB2 += __shfl_xor(sB2, m, 64);
        }
        if (L < 4) {
            gred[wv][L * 4 + 0] = sA;  gred[wv][L * 4 + 1] = sA2;
            gred[wv][L * 4 + 2] = sB;  gred[wv][L * 4 + 3] = sB2;
        }
    }
    __syncthreads();
    if (tid < 16) {
        float v = gred[0][tid] + gred[1][tid] + gred[2][tid] + gred[3][tid];
        int part = tid >> 2, stat = tid & 3;
        int g2 = b * 8 + part * 2 + (stat >> 1);
        atomicAdd((stat & 1) ? &gsq[g2] : &gsum[g2], v);
    }
}

// ---------------- fused GN + SiLU + conv_out (+ loss scalars) ----------------
__global__ __launch_bounds__(256, 2) void k_out(
    const float* __restrict__ quant,
    const float* __restrict__ gsum, const float* __restrict__ gsq,
    const float* __restrict__ scale, const float* __restrict__ bias,
    const float* __restrict__ dw, const float* __restrict__ db,
    const float* __restrict__ ssd, float* __restrict__ losses,
    float* __restrict__ out) {

    __shared__ float nls[64 * 3 * 66];    // [ci][kh][w+1], cols 0 & 65 zero-pad
    __shared__ float sc_s[64], bi_s[64];

    const int tid = threadIdx.x;
    const int blk = blockIdx.x;
    const int b = blk >> 6, h = blk & 63;

    if (blk == 0 && tid == 0) {
        float mean = ssd[0] / 2097152.f;
        losses[0] = mean;
        losses[1] = 0.25f * mean;
    }

    if (tid < 64) {
        int grp = b * 8 + (tid >> 3);
        float m = gsum[grp] * (1.f / 32768.f);
        float var = gsq[grp] * (1.f / 32768.f) - m * m;
        float r = rsqrtf(var + 1e-5f);
        float sc = scale[tid] * r;
        sc_s[tid] = sc;
        bi_s[tid] = bias[tid] - m * sc;
    }
    for (int idx = tid; idx < 384; idx += 256) {
        int ci = idx / 6, r2 = idx % 6;
        int kh = r2 >> 1, side = r2 & 1;
        nls[ci * 198 + kh * 66 + (side ? 65 : 0)] = 0.f;
    }
    __syncthreads();

#pragma unroll
    for (int i = 0; i < 48; i++) {
        int idx = tid + i * 256;
        int w_ = idx & 63;
        int t2 = idx >> 6;                 // ci*3+kh
        int kh = t2 % 3, ci = t2 / 3;
        int hh = h + kh - 1;
        float v = 0.f;
        if (hh >= 0 && hh < 64) {
            float qv = quant[((size_t)(b * 64 + ci) << 12) + (hh << 6) + w_];
            float y = qv * sc_s[ci] + bi_s[ci];
            v = y / (1.f + expf(-y));
        }
        nls[ci * 198 + kh * 66 + w_ + 1] = v;
    }
    __syncthreads();

    const int co = tid >> 6;               // wave-uniform
    const int w_ = tid & 63;
    if (co < 3) {
        float acc = db[co];
#pragma unroll 4
        for (int ci = 0; ci < 64; ci++) {
            const float* wt = dw + (size_t)(co * 64 + ci) * 9;
#pragma unroll
            for (int kh = 0; kh < 3; kh++) {
                const float* base = nls + ci * 198 + kh * 66 + w_;
                acc = fmaf(base[0], wt[kh * 3 + 0], acc);
                acc = fmaf(base[1], wt[kh * 3 + 1], acc);
                acc = fmaf(base[2], wt[kh * 3 + 2], acc);
            }
        }
        out[((size_t)(b * 3 + co) << 12) + (h << 6) + w_] = acc;
    }
}

extern "C" void kernel_launch(void* const* d_in, const int* in_sizes, int n_in,
                              void* d_out, int out_size, void* d_ws, size_t ws_size,
                              hipStream_t stream) {
    const float* x   = (const float*)d_in[0];
    const float* ciw = (const float*)d_in[1];
    const float* cib = (const float*)d_in[2];
    const float* cb  = (const float*)d_in[3];
    const float* gsc = (const float*)d_in[4];
    const float* gbi = (const float*)d_in[5];
    const float* dw  = (const float*)d_in[6];
    const float* db  = (const float*)d_in[7];

    float* out = (float*)d_out;
    char* wsb  = (char*)d_ws;

    float*          ssd  = (float*)wsb;                       // 4B
    float*          gsum = (float*)(wsb + 64);                // 256B
    float*          gsq  = (float*)(wsb + 320);               // 256B
    float*          cn   = (float*)(wsb + 4096);              // 16KB
    unsigned short* cbh  = (unsigned short*)(wsb + 131072);   // 512KB
    unsigned short* cbl  = (unsigned short*)(wsb + 655360);   // 512KB

    float* recon  = out;                    // 98304
    float* quant  = out + 98304;            // 2097152
    float* losses = out + 98304 + NELEM;    // 2

    k_prep   <<<64,  256, 0, stream>>>(cb, cn, cbh, cbl, (int*)wsb);
    k_argmin <<<512, 256, 0, stream>>>(x, ciw, cib, cbh, cbl, cn, cb,
                                       quant, ssd, gsum, gsq);
    k_out    <<<512, 256, 0, stream>>>(quant, gsum, gsq, gsc, gbi, dw, db,
                                       ssd, losses, recon);
}